// Round 2
// baseline (207.278 us; speedup 1.0000x reference)
//
#include <hip/hip_runtime.h>
#include <hip/hip_bf16.h>

#define HWSZ 12544   // 112*112
#define WDIM 112
#define CIN  128
#define COUT 64
#define NPIX 25088   // B*HWSZ, B=2

// NATTEN window start for K=7, D=2 (general-L form of the reference formula)
__device__ __forceinline__ int window_start7x2(int idx, int L) {
    int ni = idx - 6;            // idx - nh*D, nh=3, D=2
    int imodd = idx & 1;         // idx % D
    int a = (L >> 1) << 1;       // L//D*D
    int bb = L - a;
    int right = (imodd < bb) ? (L - bb + imodd - 12) : (a + imodd - 14);
    if (ni < 0) return imodd;
    if (idx + 6 >= L) return right;
    return ni;
}

// ---------------------------------------------------------------------------
// Projection: q/k/v[p][o] = sum_c x[b,c,p] * W[o,c] + b[o]
// grid (392, 3): x-tiles of 64 pixels, y = which of Wq/Wk/Wv
// ---------------------------------------------------------------------------
__global__ __launch_bounds__(256) void proj_kernel(
    const float* __restrict__ x,
    const float* __restrict__ Wq, const float* __restrict__ bq,
    const float* __restrict__ Wk, const float* __restrict__ bk,
    const float* __restrict__ Wv, const float* __restrict__ bv,
    float* __restrict__ qkv)
{
    // pads: xs row 68 -> b128 reads along p conflict-free; wsh row 132 -> the
    // 4 distinct o's per wave land on distinct bank quads.
    __shared__ float xs[CIN][68];
    __shared__ float wsh[32][132];

    const int t    = threadIdx.x;
    const int lane = t & 63;
    const int wave = t >> 6;

    const int m = blockIdx.y;
    const float* Wm = (m == 0) ? Wq : (m == 1) ? Wk : Wv;
    const float* bm = (m == 0) ? bq : (m == 1) ? bk : bv;
    float* outm = qkv + (size_t)m * NPIX * COUT;

    const int b   = blockIdx.x / 196;
    const int hw0 = (blockIdx.x % 196) * 64;
    const float* xb = x + (size_t)b * CIN * HWSZ + hw0;

    // stage x tile: 128 c x 64 p, coalesced along p (lane = p)
    #pragma unroll
    for (int rep = 0; rep < 32; ++rep) {
        int idx = rep * 256 + t;
        int c = idx >> 6;
        int p = idx & 63;
        xs[c][p] = xb[c * HWSZ + p];
    }

    const int p0 = (lane & 15) * 4;            // 4 pixels per thread
    const int og = wave * 8 + (lane >> 4) * 2; // 2 outputs per thread (even base)

    for (int half = 0; half < 2; ++half) {
        const int obase = half * 32;
        __syncthreads();   // first pass: xs ready; second: wsh no longer read
        #pragma unroll
        for (int rep = 0; rep < 16; ++rep) {
            int idx = rep * 256 + t;
            int o = idx >> 7;
            int c = idx & 127;
            wsh[o][c] = Wm[(obase + o) * CIN + c];
        }
        __syncthreads();

        const float b0 = bm[obase + og];
        const float b1 = bm[obase + og + 1];
        float4 acc0 = make_float4(b0, b0, b0, b0);
        float4 acc1 = make_float4(b1, b1, b1, b1);

        #pragma unroll 4
        for (int cc = 0; cc < 32; ++cc) {
            float4 w0 = *(const float4*)&wsh[og][cc * 4];
            float4 w1 = *(const float4*)&wsh[og + 1][cc * 4];
            const float* w0f = (const float*)&w0;
            const float* w1f = (const float*)&w1;
            #pragma unroll
            for (int j = 0; j < 4; ++j) {
                float4 xv = *(const float4*)&xs[cc * 4 + j][p0];
                acc0.x = fmaf(xv.x, w0f[j], acc0.x);
                acc0.y = fmaf(xv.y, w0f[j], acc0.y);
                acc0.z = fmaf(xv.z, w0f[j], acc0.z);
                acc0.w = fmaf(xv.w, w0f[j], acc0.w);
                acc1.x = fmaf(xv.x, w1f[j], acc1.x);
                acc1.y = fmaf(xv.y, w1f[j], acc1.y);
                acc1.z = fmaf(xv.z, w1f[j], acc1.z);
                acc1.w = fmaf(xv.w, w1f[j], acc1.w);
            }
        }

        const float a0[4] = {acc0.x, acc0.y, acc0.z, acc0.w};
        const float a1[4] = {acc1.x, acc1.y, acc1.z, acc1.w};
        #pragma unroll
        for (int i = 0; i < 4; ++i) {
            size_t pg = (size_t)(b * HWSZ + hw0 + p0 + i);
            *(float2*)&outm[pg * COUT + obase + og] = make_float2(a0[i], a1[i]);
        }
    }
}

// ---------------------------------------------------------------------------
// Attention: one wave per pixel, lane = channel (COUT=64 = wave size)
// grid 6272 blocks x 256 threads (4 pixels per block)
// ---------------------------------------------------------------------------
__global__ __launch_bounds__(256) void attn_kernel(
    const float* __restrict__ qkv, float* __restrict__ out)
{
    __shared__ float ots[4][65];   // pad 65: transposed read is conflict-free

    const int t    = threadIdx.x;
    const int lane = t & 63;
    const int wv   = t >> 6;
    const int p    = blockIdx.x * 4 + wv;

    const int b  = p / HWSZ;
    const int hw = p - b * HWSZ;
    const int h  = hw / WDIM;
    const int w  = hw - h * WDIM;

    const float* q  = qkv;
    const float* kk = qkv + (size_t)NPIX * COUT;
    const float* vv = qkv + 2 * (size_t)NPIX * COUT;

    const float qval = q[(size_t)p * COUT + lane] * 0.125f;  // scale = 64^-0.5

    const int hs  = window_start7x2(h, WDIM);
    const int ws0 = window_start7x2(w, WDIM);

    float myscore = -INFINITY;  // lanes 49..63 stay -inf -> weight 0
    int   mynbr   = 0;

    #pragma unroll
    for (int i = 0; i < 7; ++i) {
        const int rowbase = b * HWSZ + (hs + 2 * i) * WDIM + ws0;
        #pragma unroll
        for (int j = 0; j < 7; ++j) {
            const int n  = i * 7 + j;
            const int np = rowbase + 2 * j;
            float prod = qval * kk[(size_t)np * COUT + lane];
            #pragma unroll
            for (int s = 1; s < 64; s <<= 1)
                prod += __shfl_xor(prod, s, 64);
            if (lane == n) { myscore = prod; mynbr = np; }
        }
    }

    // softmax across the 49 scores (held one per lane)
    float mx = myscore;
    #pragma unroll
    for (int s = 1; s < 64; s <<= 1)
        mx = fmaxf(mx, __shfl_xor(mx, s, 64));
    const float e = (lane < 49) ? __expf(myscore - mx) : 0.0f;
    float dsum = e;
    #pragma unroll
    for (int s = 1; s < 64; s <<= 1)
        dsum += __shfl_xor(dsum, s, 64);
    const float wt = e / dsum;

    // out[c] = sum_n wt_n * v[nbr_n][c]; broadcast via readlane (const index)
    float acc = 0.0f;
    #pragma unroll
    for (int n = 0; n < 49; ++n) {
        const float wn = __shfl(wt, n, 64);
        const int   np = __shfl(mynbr, n, 64);
        acc = fmaf(wn, vv[(size_t)np * COUT + lane], acc);
    }

    // stage to LDS, write (B,C,H,W) with 16B-coalesced segments
    ots[wv][lane] = acc;
    __syncthreads();
    {
        const int pix = t & 3;          // pixel within block
        const int c   = t >> 2;         // channel
        const int p2  = blockIdx.x * 4; // block-base pixel (never straddles b)
        const int b2  = p2 / HWSZ;
        const int hw2 = p2 - b2 * HWSZ;
        out[(size_t)(b2 * COUT + c) * HWSZ + hw2 + pix] = ots[pix][c];
    }
}

// ---------------------------------------------------------------------------
extern "C" void kernel_launch(void* const* d_in, const int* in_sizes, int n_in,
                              void* d_out, int out_size, void* d_ws, size_t ws_size,
                              hipStream_t stream) {
    const float* x  = (const float*)d_in[0];
    const float* Wq = (const float*)d_in[1];
    const float* bq = (const float*)d_in[2];
    const float* Wk = (const float*)d_in[3];
    const float* bk = (const float*)d_in[4];
    const float* Wv = (const float*)d_in[5];
    const float* bv = (const float*)d_in[6];
    float* out = (float*)d_out;

    float* qkv = (float*)d_ws;   // [3][NPIX][COUT] fp32 = 19.3 MB

    dim3 gproj(392, 3);
    proj_kernel<<<gproj, dim3(256), 0, stream>>>(x, Wq, bq, Wk, bk, Wv, bv, qkv);
    attn_kernel<<<dim3(6272), dim3(256), 0, stream>>>(qkv, out);
}

// Round 4
// 122.265 us; speedup vs baseline: 1.6953x; 1.6953x over previous
//
#include <hip/hip_runtime.h>
#include <hip/hip_bf16.h>

#define HWSZ 12544   // 112*112
#define WDIM 112
#define CIN  128
#define NPIX 25088   // B*HWSZ, B=2

typedef __attribute__((ext_vector_type(8))) short          short8;
typedef __attribute__((ext_vector_type(4))) float          float4v;
typedef __attribute__((ext_vector_type(4))) unsigned short ushort4v;

// NATTEN window start for K=7, D=2
__device__ __forceinline__ int window_start7x2(int idx, int L) {
    int ni = idx - 6;            // idx - nh*D
    int imodd = idx & 1;
    int a = (L >> 1) << 1;
    int bb = L - a;
    int right = (imodd < bb) ? (L - bb + imodd - 12) : (a + imodd - 14);
    if (ni < 0) return imodd;
    if (idx + 6 >= L) return right;
    return ni;
}

__device__ __forceinline__ unsigned short f2bf(float f) {
    __hip_bfloat16 h = __float2bfloat16(f);
    return *(unsigned short*)&h;
}
__device__ __forceinline__ float bf2f(unsigned short u) {
    __hip_bfloat16 h = *(__hip_bfloat16*)&u;
    return __bfloat162float(h);
}

// ---------------------------------------------------------------------------
// Projection GEMM via MFMA: qkv[m][pix][o] = sum_c x[b,c,pix] * Wm[o,c] + bm[o]
// grid (392, 3) x 256 thr. q (m==0) pre-scaled by 0.125. Output bf16.
// ---------------------------------------------------------------------------
__global__ __launch_bounds__(256) void proj_mfma(
    const float* __restrict__ x,
    const float* __restrict__ Wq, const float* __restrict__ bq,
    const float* __restrict__ Wk, const float* __restrict__ bk,
    const float* __restrict__ Wv, const float* __restrict__ bv,
    unsigned short* __restrict__ qkv)
{
    __shared__ __align__(16) unsigned short xs[64][136];   // [px][c], pad 8
    __shared__ __align__(16) unsigned short wsb[64][136];  // [out][c], pad 8

    const int t = threadIdx.x, lane = t & 63, wv = t >> 6;
    const int m = blockIdx.y;
    const float* Wm = (m == 0) ? Wq : (m == 1) ? Wk : Wv;
    const float* bm = (m == 0) ? bq : (m == 1) ? bk : bv;
    unsigned short* outm = qkv + (size_t)m * NPIX * 64;

    const int pix0 = blockIdx.x * 64;
    const int b    = pix0 / HWSZ;
    const int hw0  = pix0 - b * HWSZ;
    const float* xb = x + (size_t)b * CIN * HWSZ + hw0;

    // stage x tile (transpose to [px][c]); global reads coalesced along px
    #pragma unroll
    for (int i = 0; i < 32; ++i) {
        int c = wv * 32 + i;
        xs[lane][c] = f2bf(xb[(size_t)c * HWSZ + lane]);
    }
    // stage W tile [out][c]
    #pragma unroll
    for (int i = 0; i < 8; ++i) {
        int u = t + 256 * i;
        int o = u >> 5, cq = (u & 31) * 4;
        float4 w4 = *(const float4*)&Wm[o * 128 + cq];
        ushort4v s4 = { f2bf(w4.x), f2bf(w4.y), f2bf(w4.z), f2bf(w4.w) };
        *(ushort4v*)&wsb[o][cq] = s4;
    }
    __syncthreads();

    // wave wv computes px-tile [wv*16, wv*16+16) x all 64 outs; K = Cin = 128
    short8 af[4];
    #pragma unroll
    for (int kc = 0; kc < 4; ++kc)
        af[kc] = *(const short8*)&xs[wv * 16 + (lane & 15)][kc * 32 + (lane >> 4) * 8];

    float4v acc[4] = {{0,0,0,0},{0,0,0,0},{0,0,0,0},{0,0,0,0}};
    #pragma unroll
    for (int kc = 0; kc < 4; ++kc) {
        #pragma unroll
        for (int nt = 0; nt < 4; ++nt) {
            short8 bf = *(const short8*)&wsb[nt * 16 + (lane & 15)][kc * 32 + (lane >> 4) * 8];
            acc[nt] = __builtin_amdgcn_mfma_f32_16x16x32_bf16(af[kc], bf, acc[nt], 0, 0, 0);
        }
    }

    const float scale = (m == 0) ? 0.125f : 1.0f;   // fold 64^-0.5 into q
    #pragma unroll
    for (int nt = 0; nt < 4; ++nt) {
        int o = nt * 16 + (lane & 15);
        float bias = bm[o];
        #pragma unroll
        for (int r = 0; r < 4; ++r) {
            int px = wv * 16 + (lane >> 4) * 4 + r;   // D: row=(lane>>4)*4+reg
            outm[(size_t)(pix0 + px) * 64 + o] = f2bf((acc[nt][r] + bias) * scale);
        }
    }
}

// ---------------------------------------------------------------------------
// Attention: tile = 16 same-parity pixels of one row. Key union 7x22=154 keys
// (padded 160). Dense S via MFMA (K=64!), mask, softmax, PV via MFMA (K=160).
// grid 1792 = 2(b) * 112(h) * 2(parity) * 4(px-group)
// ---------------------------------------------------------------------------
__global__ __launch_bounds__(256) void attn_mfma(
    const unsigned short* __restrict__ qkv, float* __restrict__ out)
{
    __shared__ __align__(16) unsigned short ks[160][72];   // [key][ch]
    __shared__ __align__(16) unsigned short vs[64][168];   // [ch][key] (V^T)
    __shared__ __align__(16) unsigned short qs[16][72];    // [px][ch]
    __shared__ __align__(16) unsigned short ps[16][168];   // S then P, bf16

    const int t = threadIdx.x, lane = t & 63, wv = t >> 6;
    const int bx  = blockIdx.x;
    const int b   = bx / 896;  const int rem = bx - b * 896;
    const int h   = rem >> 3;  const int sub = rem & 7;
    const int g   = sub & 1;                     // w parity
    const int pbi = sub >> 1;
    const int pb  = (pbi < 3) ? pbi * 16 : 40;   // last tile overlaps (benign)

    const int hs  = window_start7x2(h, WDIM);    // key rows: hs + 2i
    const int w0  = 2 * pb + g;
    const int ws0 = window_start7x2(w0, WDIM);   // key cols: ws0 + 2c, c<22
    const int pixbase = b * HWSZ;

    const unsigned short* qg = qkv;
    const unsigned short* kg = qkv + (size_t)NPIX * 64;
    const unsigned short* vg = qkv + 2 * (size_t)NPIX * 64;

    // ---- stage Q: 16 px x 64 ch
    {
        int px = t >> 4, cq = (t & 15) * 4;
        int w = 2 * (pb + px) + g;
        *(ushort4v*)&qs[px][cq] =
            *(const ushort4v*)(qg + (size_t)(pixbase + h * WDIM + w) * 64 + cq);
    }
    // ---- stage K: key u = i*22+c -> pixel (hs+2i, ws0+2c); clamp addr only
    {
        int cq = (t & 15) * 4;
        for (int u = (t >> 4); u < 154; u += 16) {
            int i = u / 22, c = u - i * 22;
            int kw = ws0 + 2 * c; if (kw > 111) kw = 111;  // garbage ok: masked
            int kp = pixbase + (hs + 2 * i) * WDIM + kw;
            *(ushort4v*)&ks[u][cq] = *(const ushort4v*)(kg + (size_t)kp * 64 + cq);
        }
    }
    // ---- stage V transposed; out-of-range cols MUST be zero (P=0*NaN guard)
    {
        for (int u = wv; u < 154; u += 4) {
            int i = u / 22, c = u - i * 22;
            int kw = ws0 + 2 * c;
            unsigned short val = 0;
            if (kw <= 111) {
                int kp = pixbase + (hs + 2 * i) * WDIM + kw;
                val = vg[(size_t)kp * 64 + lane];
            }
            vs[lane][u] = val;
        }
        if (t < 64) {
            #pragma unroll
            for (int c2 = 154; c2 < 160; ++c2) vs[t][c2] = 0;
        }
    }
    __syncthreads();

    // per-lane window bases for its 4 D-rows (px = (lane>>4)*4 + r)
    int cb_r[4];
    #pragma unroll
    for (int r = 0; r < 4; ++r) {
        int px = (lane >> 4) * 4 + r;
        cb_r[r] = (window_start7x2(2 * (pb + px) + g, WDIM) - ws0) >> 1;
    }

    // ---- scores: S[16][160] = Q(16x64) * K^T(64x160); K-dim = 64 -> kc<2
    short8 af[2];
    #pragma unroll
    for (int kc = 0; kc < 2; ++kc)
        af[kc] = *(const short8*)&qs[lane & 15][kc * 32 + (lane >> 4) * 8];

    for (int nt = wv; nt < 10; nt += 4) {
        float4v acc = {0,0,0,0};
        int keyb = nt * 16 + (lane & 15);
        #pragma unroll
        for (int kc = 0; kc < 2; ++kc) {
            short8 bf = *(const short8*)&ks[keyb][kc * 32 + (lane >> 4) * 8];
            acc = __builtin_amdgcn_mfma_f32_16x16x32_bf16(af[kc], bf, acc, 0, 0, 0);
        }
        int i = keyb / 22, c = keyb - i * 22;
        (void)i;
        bool colok = (keyb < 154);
        #pragma unroll
        for (int r = 0; r < 4; ++r) {
            bool valid = colok && ((unsigned)(c - cb_r[r]) < 7u);
            float sv = valid ? acc[r] : -1e30f;   // unconditional overwrite
            int px = (lane >> 4) * 4 + r;
            ps[px][keyb] = f2bf(sv);
        }
    }
    __syncthreads();

    // ---- softmax: 16 threads per px-row, 4-stage butterflies only
    {
        const int row = t >> 4, slot = t & 15;
        float sv[10]; float mx = -1e30f;
        #pragma unroll
        for (int k2 = 0; k2 < 10; ++k2) {
            sv[k2] = bf2f(ps[row][slot + 16 * k2]);
            mx = fmaxf(mx, sv[k2]);
        }
        #pragma unroll
        for (int msk = 1; msk < 16; msk <<= 1)
            mx = fmaxf(mx, __shfl_xor(mx, msk, 64));
        float sum = 0.0f;
        #pragma unroll
        for (int k2 = 0; k2 < 10; ++k2) {
            sv[k2] = __expf(sv[k2] - mx);   // masked -> exp(-huge) = 0
            sum += sv[k2];
        }
        #pragma unroll
        for (int msk = 1; msk < 16; msk <<= 1)
            sum += __shfl_xor(sum, msk, 64);
        float rinv = 1.0f / sum;
        #pragma unroll
        for (int k2 = 0; k2 < 10; ++k2)
            ps[row][slot + 16 * k2] = f2bf(sv[k2] * rinv);
    }
    __syncthreads();

    // ---- PV: O[16][64] = P(16x160) * V(160x64); wave wv owns ch-tile wv
    float4v oacc = {0,0,0,0};
    #pragma unroll
    for (int kc = 0; kc < 5; ++kc) {
        short8 pa = *(const short8*)&ps[lane & 15][kc * 32 + (lane >> 4) * 8];
        short8 vb = *(const short8*)&vs[wv * 16 + (lane & 15)][kc * 32 + (lane >> 4) * 8];
        oacc = __builtin_amdgcn_mfma_f32_16x16x32_bf16(pa, vb, oacc, 0, 0, 0);
    }
    {
        int ch = wv * 16 + (lane & 15);
        float* ob = out + (size_t)(b * 64 + ch) * HWSZ + h * WDIM;
        #pragma unroll
        for (int r = 0; r < 4; ++r) {
            int px = (lane >> 4) * 4 + r;
            ob[2 * (pb + px) + g] = oacc[r];
        }
    }
}

// ---------------------------------------------------------------------------
extern "C" void kernel_launch(void* const* d_in, const int* in_sizes, int n_in,
                              void* d_out, int out_size, void* d_ws, size_t ws_size,
                              hipStream_t stream) {
    const float* x  = (const float*)d_in[0];
    const float* Wq = (const float*)d_in[1];
    const float* bq = (const float*)d_in[2];
    const float* Wk = (const float*)d_in[3];
    const float* bk = (const float*)d_in[4];
    const float* Wv = (const float*)d_in[5];
    const float* bv = (const float*)d_in[6];
    float* out = (float*)d_out;

    unsigned short* qkv = (unsigned short*)d_ws;  // [3][NPIX][64] bf16 = 9.6 MB

    proj_mfma<<<dim3(392, 3), dim3(256), 0, stream>>>(x, Wq, bq, Wk, bk, Wv, bv, qkv);
    attn_mfma<<<dim3(1792), dim3(256), 0, stream>>>(qkv, out);
}

// Round 5
// 96.920 us; speedup vs baseline: 2.1386x; 1.2615x over previous
//
#include <hip/hip_runtime.h>
#include <hip/hip_bf16.h>

#define HWSZ 12544   // 112*112
#define WDIM 112
#define CIN  128
#define NPIX 25088   // B*HWSZ, B=2
#define VPITCH 68    // vsn row pitch (ushorts): 8B-aligned rows, conflict-free u16 gather

typedef __attribute__((ext_vector_type(8))) short          short8;
typedef __attribute__((ext_vector_type(4))) float          float4v;
typedef __attribute__((ext_vector_type(4))) unsigned short ushort4v;

// NATTEN window start for K=7, D=2
__device__ __forceinline__ int window_start7x2(int idx, int L) {
    int ni = idx - 6;
    int imodd = idx & 1;
    int a = (L >> 1) << 1;
    int bb = L - a;
    int right = (imodd < bb) ? (L - bb + imodd - 12) : (a + imodd - 14);
    if (ni < 0) return imodd;
    if (idx + 6 >= L) return right;
    return ni;
}

__device__ __forceinline__ unsigned short f2bf(float f) {
    __hip_bfloat16 h = __float2bfloat16(f);
    return *(unsigned short*)&h;
}
__device__ __forceinline__ float bf2f(unsigned short u) {
    __hip_bfloat16 h = *(__hip_bfloat16*)&u;
    return __bfloat162float(h);
}

// ---------------------------------------------------------------------------
// Projection GEMM via MFMA. A-fragments gathered directly from x (global);
// only W staged in LDS. grid (392, 3) x 256 thr. q pre-scaled by 0.125.
// ---------------------------------------------------------------------------
__global__ __launch_bounds__(256) void proj_mfma(
    const float* __restrict__ x,
    const float* __restrict__ Wq, const float* __restrict__ bq,
    const float* __restrict__ Wk, const float* __restrict__ bk,
    const float* __restrict__ Wv, const float* __restrict__ bv,
    unsigned short* __restrict__ qkv)
{
    __shared__ __align__(16) unsigned short wsb[64][136];  // [out][c], pad 8

    const int t = threadIdx.x, lane = t & 63, wv = t >> 6, quad = lane >> 4;
    const int m = blockIdx.y;
    const float* Wm = (m == 0) ? Wq : (m == 1) ? Wk : Wv;
    const float* bm = (m == 0) ? bq : (m == 1) ? bk : bv;
    unsigned short* outm = qkv + (size_t)m * NPIX * 64;

    const int pix0 = blockIdx.x * 64;           // HWSZ % 64 == 0: no b-straddle
    const int b    = pix0 / HWSZ;
    const int hw0  = pix0 - b * HWSZ;
    const float* xb = x + (size_t)b * CIN * HWSZ;

    // stage W tile [out][c] (bf16)
    #pragma unroll
    for (int i = 0; i < 8; ++i) {
        int u = t + 256 * i;
        int o = u >> 5, cq = (u & 31) * 4;
        float4 w4 = *(const float4*)&Wm[o * 128 + cq];
        ushort4v s4 = { f2bf(w4.x), f2bf(w4.y), f2bf(w4.z), f2bf(w4.w) };
        *(ushort4v*)&wsb[o][cq] = s4;
    }

    // A-fragments direct from global: px = wv*16 + (lane&15), ch = kc*32+quad*8+j
    const int hwpx = hw0 + wv * 16 + (lane & 15);
    short8 af[4];
    #pragma unroll
    for (int kc = 0; kc < 4; ++kc) {
        #pragma unroll
        for (int j = 0; j < 8; ++j) {
            int c = kc * 32 + quad * 8 + j;
            af[kc][j] = (short)f2bf(xb[(size_t)c * HWSZ + hwpx]);
        }
    }
    __syncthreads();

    float4v acc[4] = {{0,0,0,0},{0,0,0,0},{0,0,0,0},{0,0,0,0}};
    #pragma unroll
    for (int kc = 0; kc < 4; ++kc) {
        #pragma unroll
        for (int nt = 0; nt < 4; ++nt) {
            short8 bf = *(const short8*)&wsb[nt * 16 + (lane & 15)][kc * 32 + quad * 8];
            acc[nt] = __builtin_amdgcn_mfma_f32_16x16x32_bf16(af[kc], bf, acc[nt], 0, 0, 0);
        }
    }

    const float scale = (m == 0) ? 0.125f : 1.0f;   // fold 64^-0.5 into q
    #pragma unroll
    for (int nt = 0; nt < 4; ++nt) {
        int o = nt * 16 + (lane & 15);
        float bias = bm[o];
        #pragma unroll
        for (int r = 0; r < 4; ++r) {
            int px = wv * 16 + quad * 4 + r;        // D: row = quad*4 + reg
            outm[(size_t)(pix0 + px) * 64 + o] = f2bf((acc[r==r?nt:nt][r] + bias) * scale);
        }
    }
}

// ---------------------------------------------------------------------------
// Attention: tile = 16 same-parity pixels of one row; key union 7x22=154
// (padded 160). Q/K fragments direct from global; V staged natural [key][ch]
// in LDS, PV B-fragments via u16 gather. LDS ~27 KB, 2 barriers.
// grid 1792 = 2(b) * 112(h) * 2(parity) * 4(px-group)
// ---------------------------------------------------------------------------
__global__ __launch_bounds__(256) void attn_mfma(
    const unsigned short* __restrict__ qkv, float* __restrict__ out)
{
    __shared__ __align__(16) unsigned short vsn[160 * VPITCH]; // [key][ch]
    __shared__ __align__(16) unsigned short ps[16 * 168];      // [px][key]

    const int t = threadIdx.x, lane = t & 63, wv = t >> 6, quad = lane >> 4;
    const int bx  = blockIdx.x;
    const int b   = bx / 896;  const int rem = bx - b * 896;
    const int h   = rem >> 3;  const int sub = rem & 7;
    const int g   = sub & 1;
    const int pbi = sub >> 1;
    const int pb  = (pbi < 3) ? pbi * 16 : 40;   // last tile overlaps (benign)

    const int hs  = window_start7x2(h, WDIM);
    const int ws0 = window_start7x2(2 * pb + g, WDIM);
    const int pixbase = b * HWSZ;

    const unsigned short* qg = qkv;
    const unsigned short* kg = qkv + (size_t)NPIX * 64;
    const unsigned short* vg = qkv + 2 * (size_t)NPIX * 64;

    // ---- stage V natural [key][ch], vectorized b64 chunks (4 ch each)
    for (int u = t; u < 154 * 16; u += 256) {
        int key = u >> 4, cc = (u & 15) * 4;
        int i = (unsigned)key / 22u, c = key - i * 22;
        int kw = ws0 + 2 * c; if (kw > 111) kw = 111;   // clamp: masked anyway
        int kp = pixbase + (hs + 2 * i) * WDIM + kw;
        *(ushort4v*)&vsn[key * VPITCH + cc] =
            *(const ushort4v*)(vg + (size_t)kp * 64 + cc);
    }
    // zero pad keys 154..159 (P=0 there, but LDS garbage could be NaN)
    for (int u = t; u < 6 * VPITCH; u += 256) vsn[154 * VPITCH + u] = 0;

    // ---- Q A-fragments direct from global
    const int qpix = pixbase + h * WDIM + 2 * (pb + (lane & 15)) + g;
    short8 af[2];
    #pragma unroll
    for (int kc = 0; kc < 2; ++kc)
        af[kc] = *(const short8*)(qg + (size_t)qpix * 64 + kc * 32 + quad * 8);

    // per-lane window bases for its 4 D-rows (px = quad*4 + r)
    int cb_r[4];
    #pragma unroll
    for (int r = 0; r < 4; ++r) {
        int px = quad * 4 + r;
        cb_r[r] = (window_start7x2(2 * (pb + px) + g, WDIM) - ws0) >> 1;
    }

    // ---- scores: S[16][160] = Q(16x64) * K^T; K B-fragments direct global
    for (int nt = wv; nt < 10; nt += 4) {
        int keyb = nt * 16 + (lane & 15);
        int i = (unsigned)keyb / 22u, c = keyb - i * 22;
        int kw = ws0 + 2 * c; if (kw > 111) kw = 111;
        int kp = pixbase + (hs + 2 * i) * WDIM + kw;
        float4v acc = {0,0,0,0};
        #pragma unroll
        for (int kc = 0; kc < 2; ++kc) {
            short8 bf = *(const short8*)(kg + (size_t)kp * 64 + kc * 32 + quad * 8);
            acc = __builtin_amdgcn_mfma_f32_16x16x32_bf16(af[kc], bf, acc, 0, 0, 0);
        }
        bool colok = (keyb < 154);
        #pragma unroll
        for (int r = 0; r < 4; ++r) {
            bool valid = colok && ((unsigned)(c - cb_r[r]) < 7u);
            float sv = valid ? acc[r] : -1e30f;
            int px = quad * 4 + r;
            ps[px * 168 + keyb] = f2bf(sv);
        }
    }
    __syncthreads();

    // ---- softmax: 16 threads per px-row
    {
        const int row = t >> 4, slot = t & 15;
        float sv[10]; float mx = -1e30f;
        #pragma unroll
        for (int k2 = 0; k2 < 10; ++k2) {
            sv[k2] = bf2f(ps[row * 168 + slot + 16 * k2]);
            mx = fmaxf(mx, sv[k2]);
        }
        #pragma unroll
        for (int msk = 1; msk < 16; msk <<= 1)
            mx = fmaxf(mx, __shfl_xor(mx, msk, 64));
        float sum = 0.0f;
        #pragma unroll
        for (int k2 = 0; k2 < 10; ++k2) {
            sv[k2] = __expf(sv[k2] - mx);
            sum += sv[k2];
        }
        #pragma unroll
        for (int msk = 1; msk < 16; msk <<= 1)
            sum += __shfl_xor(sum, msk, 64);
        float rinv = 1.0f / sum;
        #pragma unroll
        for (int k2 = 0; k2 < 10; ++k2)
            ps[row * 168 + slot + 16 * k2] = f2bf(sv[k2] * rinv);
    }
    __syncthreads();

    // ---- PV: O[16][64] = P(16x160) * V(160x64); wave wv owns ch-tile wv
    const int ch = wv * 16 + (lane & 15);
    float4v oacc = {0,0,0,0};
    #pragma unroll
    for (int kc = 0; kc < 5; ++kc) {
        short8 pa = *(const short8*)&ps[(lane & 15) * 168 + kc * 32 + quad * 8];
        short8 vb;
        int kbase = (kc * 32 + quad * 8) * VPITCH + ch;
        #pragma unroll
        for (int j = 0; j < 8; ++j)
            vb[j] = (short)vsn[kbase + j * VPITCH];
        oacc = __builtin_amdgcn_mfma_f32_16x16x32_bf16(pa, vb, oacc, 0, 0, 0);
    }
    {
        float* ob = out + (size_t)(b * 64 + ch) * HWSZ + h * WDIM;
        #pragma unroll
        for (int r = 0; r < 4; ++r) {
            int px = quad * 4 + r;
            ob[2 * (pb + px) + g] = oacc[r];
        }
    }
}

// ---------------------------------------------------------------------------
extern "C" void kernel_launch(void* const* d_in, const int* in_sizes, int n_in,
                              void* d_out, int out_size, void* d_ws, size_t ws_size,
                              hipStream_t stream) {
    const float* x  = (const float*)d_in[0];
    const float* Wq = (const float*)d_in[1];
    const float* bq = (const float*)d_in[2];
    const float* Wk = (const float*)d_in[3];
    const float* bk = (const float*)d_in[4];
    const float* Wv = (const float*)d_in[5];
    const float* bv = (const float*)d_in[6];
    float* out = (float*)d_out;

    unsigned short* qkv = (unsigned short*)d_ws;  // [3][NPIX][64] bf16 = 9.6 MB

    proj_mfma<<<dim3(392, 3), dim3(256), 0, stream>>>(x, Wq, bq, Wk, bk, Wv, bv, qkv);
    attn_mfma<<<dim3(1792), dim3(256), 0, stream>>>(qkv, out);
}